// Round 7
// baseline (337.640 us; speedup 1.0000x reference)
//
#include <hip/hip_runtime.h>
#include <math.h>

typedef unsigned int uint;
typedef unsigned short ushort;
typedef short short8 __attribute__((ext_vector_type(8)));
typedef float f32x4 __attribute__((ext_vector_type(4)));

#define B_ 2048
#define N_ 256
#define D_ 64
#define ND_ 16384
#define NN_ 65536
#define KIDX_ 52428u
#define NGROUPS 32   // split-K over node groups (8 nodes each) for the fused gp partials

// ---------------- ws layout (bytes) ----------------
#define WS_W1T    ((size_t)0)                    // packed W1 B-frags bf16 : 2 MiB
#define WS_W2T    ((size_t)2*1024*1024)          // packed W2 B-frags bf16 : 2 MiB
#define WS_EFF    ((size_t)4*1024*1024)          // gpW1eff B-frags bf16 [256 nodes][4096] : 2 MiB
#define WS_GPARTS ((size_t)8*1024*1024)          // f32 [32][2048][64] : 16 MiB
#define WS_SCAL   ((size_t)24*1024*1024)         // threshold scalar

__device__ __forceinline__ ushort f2bf(float f) {
    uint u = __float_as_uint(f);
    u += 0x7fffu + ((u >> 16) & 1u);
    return (ushort)(u >> 16);
}
__device__ __forceinline__ float bf2f(ushort u) { return __uint_as_float(((uint)u) << 16); }

// exact float sigmoid via correctly-rounded double exp (matches numpy; verified)
__device__ __forceinline__ float sigmoid_exact(float a) {
    float t = (float)exp(-(double)a);
    return 1.0f / (1.0f + t);
}

// float bits -> ascending-order uint key (same transform as prior verified rounds)
__device__ __forceinline__ uint f2key(uint bits) {
    return bits ^ ((bits & 0x80000000u) ? 0xFFFFFFFFu : 0x80000000u);
}

// B-fragment offset for 16x16x32 bf16: element (e=outcol, k) of a 64x64 W-slice.
__device__ __forceinline__ int wfrag_off(int e, int k) {
    return ((((e >> 4) * 2 + (k >> 5)) * 4 + ((k >> 3) & 3)) * 16 + (e & 15)) * 8 + (k & 7);
}

// A-fragment offset (local j in [0,64), i in [0,256))
__device__ __forceinline__ int afrag_off(int jl, int i) {
    return (((((jl >> 4) * 8 + (i >> 5)) * 4 + ((i >> 3) & 3)) * 16) + (jl & 15)) * 8 + (i & 7);
}

// ---------------- K1: radix select (block 0, register-resident 2-bit tournament) +
// weight convert (blocks 1..128, four 256-thread quarters per block) ------------------
__global__ __launch_bounds__(1024) void k_cvt_radix(const float* __restrict__ W1,
                                                    const float* __restrict__ W2,
                                                    const float* __restrict__ adj_param,
                                                    ushort* __restrict__ W1f,
                                                    ushort* __restrict__ W2f,
                                                    uint* __restrict__ scal) {
    __shared__ uint SH[8200] __attribute__((aligned(16)));
    int bid = blockIdx.x, tid = threadIdx.x;

    if (bid != 0) {
        // ---- convert: quarter q handles matrix m ----
        int q = tid >> 8, t = tid & 255;
        int m = (bid - 1) * 4 + q;
        ushort* P = (ushort*)SH + q * 4096;
        const float* src = (m < 256) ? W1 + (size_t)m * 4096 : W2 + (size_t)(m - 256) * 4096;
#pragma unroll
        for (int i = 0; i < 16; i++) {
            int idx = i * 256 + t;
            int k = idx >> 6, e = idx & 63;   // src is [k][e]
            P[wfrag_off(e, k)] = f2bf(src[idx]);
        }
        __syncthreads();
        ushort* dst = (m < 256) ? W1f + (size_t)m * 4096 : W2f + (size_t)(m - 256) * 4096;
#pragma unroll
        for (int i = 0; i < 2; i++)
            ((uint4*)dst)[i * 256 + t] = ((const uint4*)P)[i * 256 + t];
        return;
    }

    // ---- radix block: 64 keys per thread held in 16 static uint4 regs; 16 passes of
    // 2 bits; counts via shfl_xor wave-reduce + 1 LDS slot/wave; ONE barrier per pass
    // (parity-double-buffered totals kill the WAR barrier). NO LDS atomics.
    uint* tot = SH;                 // [2 parity][16 waves][3 counters]
    int wid = tid >> 6;
    const uint4* pv = (const uint4*)adj_param;
    uint4 A[16];
#pragma unroll
    for (int i = 0; i < 16; i++) A[i] = pv[i * 1024 + tid];
#pragma unroll
    for (int i = 0; i < 16; i++) {
        A[i].x = f2key(A[i].x); A[i].y = f2key(A[i].y);
        A[i].z = f2key(A[i].z); A[i].w = f2key(A[i].w);
    }

    uint pref = 0;
    uint rank = KIDX_;
#pragma unroll 1
    for (int p = 0; p < 16; p++) {
        int b = 30 - 2 * p;
        uint mask = (p == 0) ? 0u : (0xFFFFFFFFu << (b + 2));
        uint c0 = 0, c1 = 0, c2 = 0;
#pragma unroll
        for (int i = 0; i < 16; i++) {
#define CNT_(K) { uint k_ = (K); if (((k_ ^ pref) & mask) == 0u) { \
                    uint d_ = (k_ >> b) & 3u; \
                    c0 += (d_ == 0u); c1 += (d_ == 1u); c2 += (d_ == 2u); } }
            CNT_(A[i].x) CNT_(A[i].y) CNT_(A[i].z) CNT_(A[i].w)
#undef CNT_
        }
#pragma unroll
        for (int o = 1; o < 64; o <<= 1) {
            c0 += __shfl_xor(c0, o, 64);
            c1 += __shfl_xor(c1, o, 64);
            c2 += __shfl_xor(c2, o, 64);
        }
        if ((tid & 63) == 0) {
            uint* s = tot + (p & 1) * 48 + wid * 3;
            s[0] = c0; s[1] = c1; s[2] = c2;
        }
        __syncthreads();
        uint t0 = 0, t1 = 0, t2 = 0;
#pragma unroll
        for (int w = 0; w < 16; w++) {
            const uint* s = tot + (p & 1) * 48 + w * 3;
            t0 += s[0]; t1 += s[1]; t2 += s[2];
        }
        uint digit;
        if (rank < t0) { digit = 0u; }
        else if (rank < t0 + t1) { digit = 1u; rank -= t0; }
        else if (rank < t0 + t1 + t2) { digit = 2u; rank -= t0 + t1; }
        else { digit = 3u; rank -= t0 + t1 + t2; }
        pref |= digit << b;
    }
    if (tid == 0) {
        uint key = pref;
        uint bits = (key & 0x80000000u) ? (key ^ 0x80000000u) : ~key;
        scal[0] = __float_as_uint(sigmoid_exact(__uint_as_float(bits)));
    }
}

// ---------------- K2: thresh+eff fused (sigmoid loop 4-way batched) -------------------
__global__ __launch_bounds__(256) void k_threff(const float* __restrict__ adj_param,
                                                const uint* __restrict__ scal,
                                                const float* __restrict__ gpW1,
                                                float* __restrict__ adj_out,
                                                ushort* __restrict__ effF) {
    __shared__ ushort adjS[16384] __attribute__((aligned(16)));  // A-frags: 64 j x 256 i
    __shared__ ushort Bf[16384] __attribute__((aligned(16)));    // 4 k-slabs x 4096 frags
    int d = blockIdx.x, jt = blockIdx.y, tid = threadIdx.x;
    float thr = __uint_as_float(scal[0]);

    {
        int jl = tid & 63;
        int jglob = jt * 64 + jl;
        int wrow = tid >> 6;          // 4 waves, 4 interleaved rows
#pragma unroll 1
        for (int i = 0; i < 16; i++) {
            float p[4];
#pragma unroll
            for (int u = 0; u < 4; u++)
                p[u] = adj_param[(size_t)((i * 4 + u) * 4 + wrow) * 256 + jglob];
#pragma unroll
            for (int u = 0; u < 4; u++) {
                int ir = (i * 4 + u) * 4 + wrow;    // 0..255
                float s = sigmoid_exact(p[u]);
                float v = (s > thr && ir != jglob) ? s : 0.0f;
                adjS[afrag_off(jl, ir)] = f2bf(v);
                if (d == 0) adj_out[(size_t)ir * 256 + jglob] = v;
            }
        }
    }
#pragma unroll
    for (int t = 0; t < 16; t++) {
        int idx = t * 256 + tid;
        int i = idx >> 4;
        int f4 = idx & 15;
        float4 v = *(const float4*)(gpW1 + ((size_t)i * 64 + d) * 64 + f4 * 4);
        int slab = i >> 6, il = i & 63, e0 = f4 * 4;
        Bf[slab * 4096 + wfrag_off(e0 + 0, il)] = f2bf(v.x);
        Bf[slab * 4096 + wfrag_off(e0 + 1, il)] = f2bf(v.y);
        Bf[slab * 4096 + wfrag_off(e0 + 2, il)] = f2bf(v.z);
        Bf[slab * 4096 + wfrag_off(e0 + 3, il)] = f2bf(v.w);
    }
    __syncthreads();
    int wid = tid >> 6, lane = tid & 63, quad = lane >> 4, l16 = lane & 15;
    f32x4 acc[4];
#pragma unroll
    for (int nt = 0; nt < 4; nt++) acc[nt] = (f32x4){0.f, 0.f, 0.f, 0.f};
#pragma unroll
    for (int ks8 = 0; ks8 < 8; ks8++) {
        short8 af = *(const short8*)&adjS[((((wid * 8 + ks8) * 4 + quad) * 16 + l16)) * 8];
        int slab = ks8 >> 1, ks = ks8 & 1;
#pragma unroll
        for (int nt = 0; nt < 4; nt++) {
            short8 bf = *(const short8*)&Bf[slab * 4096 + (((nt * 2 + ks) * 4 + quad) * 16 + l16) * 8];
            acc[nt] = __builtin_amdgcn_mfma_f32_16x16x32_bf16(af, bf, acc[nt], 0, 0, 0);
        }
    }
#pragma unroll
    for (int nt = 0; nt < 4; nt++) {
        int e = nt * 16 + l16;
#pragma unroll
        for (int r = 0; r < 4; r++) {
            int j = jt * 64 + wid * 16 + quad * 4 + r;
            float w = gpW1[((size_t)j * 64 + d) * 64 + e];
            float eff = 0.5f * (acc[nt][r] + w);
            effF[(size_t)j * 4096 + wfrag_off(e, d)] = f2bf(eff);
        }
    }
}

// ---------------- K3: fused MLP+gp (R5-verified best variant) -------------------------
// 8-node groups, 1024 blocks = 4/CU. Single-buffer LDS (33 KB) + reg-staged prefetch
// of next node's weights/x/biases.
__global__ __launch_bounds__(256, 4) void k_fused(const float* __restrict__ x,
                                                  const ushort* __restrict__ W1f,
                                                  const ushort* __restrict__ W2f,
                                                  const ushort* __restrict__ effF,
                                                  const float* __restrict__ b1,
                                                  const float* __restrict__ b2,
                                                  float* __restrict__ gparts) {
    __shared__ ushort Wf1[4096] __attribute__((aligned(16)));
    __shared__ ushort Wf2[4096] __attribute__((aligned(16)));
    __shared__ ushort Ef[4096] __attribute__((aligned(16)));
    __shared__ ushort St[4][16 * 72];    // per-wave staging (stride 72: 2-way-free banks)
    int tid = threadIdx.x;
    int g = blockIdx.x, bt = blockIdx.y;
    int wid = tid >> 6, lane = tid & 63, quad = lane >> 4, l16 = lane & 15;
    int rbase = bt * 64 + wid * 16;
    ushort* Sw = &St[wid][0];
    const float* xrow = x + (size_t)(rbase + l16) * ND_ + quad * 8;

    // ---- prologue: node 0 weights->regs->LDS, x->regs, biases->regs ----
    int n0 = g * 8;
    uint4 w1a = ((const uint4*)(W1f + (size_t)n0 * 4096))[tid];
    uint4 w1b = ((const uint4*)(W1f + (size_t)n0 * 4096))[256 + tid];
    uint4 w2a = ((const uint4*)(W2f + (size_t)n0 * 4096))[tid];
    uint4 w2b = ((const uint4*)(W2f + (size_t)n0 * 4096))[256 + tid];
    uint4 ea  = ((const uint4*)(effF + (size_t)n0 * 4096))[tid];
    uint4 eb  = ((const uint4*)(effF + (size_t)n0 * 4096))[256 + tid];
    float4 xr0, xr1, xr2, xr3;
    {
        const float* xp = xrow + (size_t)n0 * 64;
        xr0 = *(const float4*)(xp);
        xr1 = *(const float4*)(xp + 4);
        xr2 = *(const float4*)(xp + 32);
        xr3 = *(const float4*)(xp + 36);
    }
    float b1n[4], b2n[4];
#pragma unroll
    for (int nt = 0; nt < 4; nt++) {
        b1n[nt] = b1[n0 * 64 + nt * 16 + l16];
        b2n[nt] = b2[n0 * 64 + nt * 16 + l16];
    }
    ((uint4*)Wf1)[tid] = w1a;  ((uint4*)Wf1)[256 + tid] = w1b;
    ((uint4*)Wf2)[tid] = w2a;  ((uint4*)Wf2)[256 + tid] = w2b;
    ((uint4*)Ef)[tid]  = ea;   ((uint4*)Ef)[256 + tid]  = eb;

    f32x4 accg[4];
#pragma unroll
    for (int nt = 0; nt < 4; nt++) accg[nt] = (f32x4){0.f, 0.f, 0.f, 0.f};

    __syncthreads();   // node-0 weights visible

#pragma unroll 1
    for (int nl = 0; nl < 8; nl++) {
        // current node's x -> A-frags, biases -> locals (before regs are overwritten)
        short8 fa0, fa1;
        {
            short8 a;
            a[0] = (short)f2bf(xr0.x); a[1] = (short)f2bf(xr0.y);
            a[2] = (short)f2bf(xr0.z); a[3] = (short)f2bf(xr0.w);
            a[4] = (short)f2bf(xr1.x); a[5] = (short)f2bf(xr1.y);
            a[6] = (short)f2bf(xr1.z); a[7] = (short)f2bf(xr1.w);
            fa0 = a;
            short8 b;
            b[0] = (short)f2bf(xr2.x); b[1] = (short)f2bf(xr2.y);
            b[2] = (short)f2bf(xr2.z); b[3] = (short)f2bf(xr2.w);
            b[4] = (short)f2bf(xr3.x); b[5] = (short)f2bf(xr3.y);
            b[6] = (short)f2bf(xr3.z); b[7] = (short)f2bf(xr3.w);
            fa1 = b;
        }
        float bias1[4], bias2[4];
#pragma unroll
        for (int nt = 0; nt < 4; nt++) { bias1[nt] = b1n[nt]; bias2[nt] = b2n[nt]; }

        // prefetch node nl+1 into registers
        if (nl < 7) {
            int nn = g * 8 + nl + 1;
            w1a = ((const uint4*)(W1f + (size_t)nn * 4096))[tid];
            w1b = ((const uint4*)(W1f + (size_t)nn * 4096))[256 + tid];
            w2a = ((const uint4*)(W2f + (size_t)nn * 4096))[tid];
            w2b = ((const uint4*)(W2f + (size_t)nn * 4096))[256 + tid];
            ea  = ((const uint4*)(effF + (size_t)nn * 4096))[tid];
            eb  = ((const uint4*)(effF + (size_t)nn * 4096))[256 + tid];
            const float* xp = xrow + (size_t)nn * 64;
            xr0 = *(const float4*)(xp);
            xr1 = *(const float4*)(xp + 4);
            xr2 = *(const float4*)(xp + 32);
            xr3 = *(const float4*)(xp + 36);
#pragma unroll
            for (int nt = 0; nt < 4; nt++) {
                b1n[nt] = b1[nn * 64 + nt * 16 + l16];
                b2n[nt] = b2[nn * 64 + nt * 16 + l16];
            }
        }

        // layer 1
        f32x4 acc[4];
#pragma unroll
        for (int nt = 0; nt < 4; nt++) acc[nt] = (f32x4){0.f, 0.f, 0.f, 0.f};
#pragma unroll
        for (int nt = 0; nt < 4; nt++) {
            short8 bf = *(const short8*)&Wf1[(((nt * 2 + 0) * 4 + quad) * 16 + l16) * 8];
            acc[nt] = __builtin_amdgcn_mfma_f32_16x16x32_bf16(fa0, bf, acc[nt], 0, 0, 0);
        }
#pragma unroll
        for (int nt = 0; nt < 4; nt++) {
            short8 bf = *(const short8*)&Wf1[(((nt * 2 + 1) * 4 + quad) * 16 + l16) * 8];
            acc[nt] = __builtin_amdgcn_mfma_f32_16x16x32_bf16(fa1, bf, acc[nt], 0, 0, 0);
        }
#pragma unroll
        for (int nt = 0; nt < 4; nt++)
#pragma unroll
            for (int r = 0; r < 4; r++) {
                float h = fmaxf(acc[nt][r] + bias1[nt], 0.0f);
                Sw[(quad * 4 + r) * 72 + nt * 16 + l16] = f2bf(h);
            }
        // layer 2
        f32x4 acc2[4];
#pragma unroll
        for (int nt = 0; nt < 4; nt++) acc2[nt] = (f32x4){0.f, 0.f, 0.f, 0.f};
#pragma unroll
        for (int ks = 0; ks < 2; ks++) {
            short8 a2 = *(const short8*)&Sw[l16 * 72 + ks * 32 + quad * 8];
#pragma unroll
            for (int nt = 0; nt < 4; nt++) {
                short8 bf = *(const short8*)&Wf2[(((nt * 2 + ks) * 4 + quad) * 16 + l16) * 8];
                acc2[nt] = __builtin_amdgcn_mfma_f32_16x16x32_bf16(a2, bf, acc2[nt], 0, 0, 0);
            }
        }
#pragma unroll
        for (int nt = 0; nt < 4; nt++)
#pragma unroll
            for (int r = 0; r < 4; r++) {
                float v = acc2[nt][r] + bias2[nt];
                Sw[(quad * 4 + r) * 72 + nt * 16 + l16] = f2bf(v);
            }
        // gp projection
#pragma unroll
        for (int ks = 0; ks < 2; ks++) {
            short8 a3 = *(const short8*)&Sw[l16 * 72 + ks * 32 + quad * 8];
#pragma unroll
            for (int nt = 0; nt < 4; nt++) {
                short8 bf = *(const short8*)&Ef[(((nt * 2 + ks) * 4 + quad) * 16 + l16) * 8];
                accg[nt] = __builtin_amdgcn_mfma_f32_16x16x32_bf16(a3, bf, accg[nt], 0, 0, 0);
            }
        }

        if (nl < 7) {
            __syncthreads();   // WAR: all waves done reading this node's weights
            ((uint4*)Wf1)[tid] = w1a;  ((uint4*)Wf1)[256 + tid] = w1b;
            ((uint4*)Wf2)[tid] = w2a;  ((uint4*)Wf2)[256 + tid] = w2b;
            ((uint4*)Ef)[tid]  = ea;   ((uint4*)Ef)[256 + tid]  = eb;
            __syncthreads();   // RAW: next node's weights visible
        }
    }

    // write fp32 partials for this node-group
    float* gp = gparts + ((size_t)g * B_ + bt * 64) * 64;
#pragma unroll
    for (int nt = 0; nt < 4; nt++)
#pragma unroll
        for (int r = 0; r < 4; r++) {
            int b_loc = wid * 16 + quad * 4 + r;
            int e = nt * 16 + l16;
            gp[b_loc * 64 + e] = accg[nt][r];
        }
}

// ---------------- K4: reduce partials, bias+relu, gp2 (fp32); 4 rows/block ------------
__global__ __launch_bounds__(256) void k_gp2(const float* __restrict__ gparts,
                                             const float* __restrict__ gpb1,
                                             const float* __restrict__ gpW2,
                                             const float* __restrict__ gpb2,
                                             float* __restrict__ out) {
    __shared__ float gs[4][64];
    int b0 = blockIdx.x * 4, tid = threadIdx.x;
    int r = tid >> 6, e = tid & 63;
    float s = gpb1[e];
#pragma unroll
    for (int p = 0; p < NGROUPS; p++)
        s += gparts[((size_t)p * B_ + b0 + r) * 64 + e];
    gs[r][e] = fmaxf(s, 0.0f);
    __syncthreads();
    if (tid < 128) {
        int rr = tid >> 5, o = tid & 31;
        float a = gpb2[o];
#pragma unroll 8
        for (int k2 = 0; k2 < 64; k2++) a += gs[rr][k2] * gpW2[k2 * 32 + o];
        out[(size_t)(b0 + rr) * 32 + o] = a;
    }
}

extern "C" void kernel_launch(void* const* d_in, const int* in_sizes, int n_in,
                              void* d_out, int out_size, void* d_ws, size_t ws_size,
                              hipStream_t stream) {
    const float* x = (const float*)d_in[0];
    const float* adj_param = (const float*)d_in[1];
    const float* W1 = (const float*)d_in[2];
    const float* b1 = (const float*)d_in[3];
    const float* W2 = (const float*)d_in[4];
    const float* b2 = (const float*)d_in[5];
    const float* gpW1 = (const float*)d_in[6];
    const float* gpb1 = (const float*)d_in[7];
    const float* gpW2 = (const float*)d_in[8];
    const float* gpb2 = (const float*)d_in[9];

    float* out = (float*)d_out;                 // [2048*32]
    float* adj_out = (float*)d_out + NN_;       // [256*256]

    char* ws = (char*)d_ws;
    ushort* W1f = (ushort*)(ws + WS_W1T);
    ushort* W2f = (ushort*)(ws + WS_W2T);
    ushort* effF = (ushort*)(ws + WS_EFF);
    float* gparts = (float*)(ws + WS_GPARTS);
    uint* scal = (uint*)(ws + WS_SCAL);

    k_cvt_radix<<<129, 1024, 0, stream>>>(W1, W2, adj_param, W1f, W2f, scal);
    k_threff<<<dim3(64, 4), 256, 0, stream>>>(adj_param, scal, gpW1, adj_out, effF);
    k_fused<<<dim3(NGROUPS, 32), 256, 0, stream>>>(x, W1f, W2f, effF, b1, b2, gparts);
    k_gp2<<<512, 256, 0, stream>>>(gparts, gpb1, gpW2, gpb2, out);
}

// Round 8
// 273.458 us; speedup vs baseline: 1.2347x; 1.2347x over previous
//
#include <hip/hip_runtime.h>
#include <math.h>

typedef unsigned int uint;
typedef unsigned short ushort;
typedef short short8 __attribute__((ext_vector_type(8)));
typedef float f32x4 __attribute__((ext_vector_type(4)));

#define B_ 2048
#define N_ 256
#define D_ 64
#define ND_ 16384
#define NN_ 65536
#define KIDX_ 52428u
#define NGROUPS 32   // split-K over node groups (8 nodes each) for the fused gp partials

// ---------------- ws layout (bytes) ----------------
#define WS_W1T    ((size_t)0)                    // packed W1 B-frags bf16 : 2 MiB
#define WS_W2T    ((size_t)2*1024*1024)          // packed W2 B-frags bf16 : 2 MiB
#define WS_EFF    ((size_t)4*1024*1024)          // gpW1eff B-frags bf16 [256 nodes][4096] : 2 MiB
#define WS_GPARTS ((size_t)8*1024*1024)          // f32 [32][2048][64] : 16 MiB
#define WS_SCAL   ((size_t)24*1024*1024)         // threshold scalar

__device__ __forceinline__ ushort f2bf(float f) {
    uint u = __float_as_uint(f);
    u += 0x7fffu + ((u >> 16) & 1u);
    return (ushort)(u >> 16);
}
__device__ __forceinline__ float bf2f(ushort u) { return __uint_as_float(((uint)u) << 16); }

// exact float sigmoid via correctly-rounded double exp (matches numpy; verified)
__device__ __forceinline__ float sigmoid_exact(float a) {
    float t = (float)exp(-(double)a);
    return 1.0f / (1.0f + t);
}

// float bits -> ascending-order uint key (same transform as prior verified rounds)
__device__ __forceinline__ uint f2key(uint bits) {
    return bits ^ ((bits & 0x80000000u) ? 0xFFFFFFFFu : 0x80000000u);
}

// B-fragment offset for 16x16x32 bf16: element (e=outcol, k) of a 64x64 W-slice.
__device__ __forceinline__ int wfrag_off(int e, int k) {
    return ((((e >> 4) * 2 + (k >> 5)) * 4 + ((k >> 3) & 3)) * 16 + (e & 15)) * 8 + (k & 7);
}

// A-fragment offset (local j in [0,64), i in [0,256))
__device__ __forceinline__ int afrag_off(int jl, int i) {
    return (((((jl >> 4) * 8 + (i >> 5)) * 4 + ((i >> 3) & 3)) * 16) + (jl & 15)) * 8 + (i & 7);
}

// ---------------- K1: radix select (block 0: 3-level MSD histogram, no spills) +
// weight convert (blocks 1..128, four 256-thread quarters per block) ------------------
__global__ __launch_bounds__(1024) void k_cvt_radix(const float* __restrict__ W1,
                                                    const float* __restrict__ W2,
                                                    const float* __restrict__ adj_param,
                                                    ushort* __restrict__ W1f,
                                                    ushort* __restrict__ W2f,
                                                    uint* __restrict__ scal) {
    __shared__ uint SH[16402] __attribute__((aligned(16)));   // 64 KB hist + scan scratch
    int bid = blockIdx.x, tid = threadIdx.x;

    if (bid != 0) {
        // ---- convert: quarter q handles matrix m ----
        int q = tid >> 8, t = tid & 255;
        int m = (bid - 1) * 4 + q;
        ushort* P = (ushort*)SH + q * 4096;
        const float* src = (m < 256) ? W1 + (size_t)m * 4096 : W2 + (size_t)(m - 256) * 4096;
#pragma unroll
        for (int i = 0; i < 16; i++) {
            int idx = i * 256 + t;
            int k = idx >> 6, e = idx & 63;   // src is [k][e]
            P[wfrag_off(e, k)] = f2bf(src[idx]);
        }
        __syncthreads();
        ushort* dst = (m < 256) ? W1f + (size_t)m * 4096 : W2f + (size_t)(m - 256) * 4096;
#pragma unroll
        for (int i = 0; i < 2; i++)
            ((uint4*)dst)[i * 256 + t] = ((const uint4*)P)[i * 256 + t];
        return;
    }

    // ---- radix block: 3-level MSD histogram select (11+11+10 bits).
    // No per-thread key storage (R7's A[16] spilled to scratch: VGPR=64, 4 MB scratch
    // re-reads). Each level re-reads the 256 KB array from L2 coalesced; LDS hist with
    // 8 sub-slots cuts hot-bin atomic serialization (keys concentrate in ~20 exponent
    // bins for N(0,0.1) data). Exact selection: same key transform, duplicates counted.
    uint* hist = SH;                  // up to [2048][8] uint = 64 KB
    uint* wsum = SH + 16384;          // 16 wave totals
    uint* bc   = SH + 16400;          // bc[0]=chosen bin, bc[1]=residual rank
    const uint4* pv = (const uint4*)adj_param;
    uint rank = KIDX_;
    uint pref = 0u;
#pragma unroll 1
    for (int lvl = 0; lvl < 3; lvl++) {
        int nb  = (lvl == 2) ? 1024 : 2048;
        int sh  = (lvl == 0) ? 21 : (lvl == 1) ? 10 : 0;
        uint pm = (lvl == 0) ? 0u : (lvl == 1) ? 0xFFE00000u : 0xFFFFFC00u;
        for (int i = tid; i < nb * 8; i += 1024) hist[i] = 0u;
        __syncthreads();
        int sub = tid & 7;
#pragma unroll 1
        for (int i = 0; i < 16; i++) {
            uint4 v = pv[i * 1024 + tid];
#define H_(B) { uint k_ = f2key(B); if (((k_ ^ pref) & pm) == 0u) \
                atomicAdd(&hist[(((k_ >> sh) & (uint)(nb - 1)) << 3) + sub], 1u); }
            H_(v.x) H_(v.y) H_(v.z) H_(v.w)
#undef H_
        }
        __syncthreads();
        int bpt = nb >> 10;                // bins per thread: 2 (lvl 0/1) or 1 (lvl 2)
        int b0 = tid * bpt;
        uint c0 = 0, c1 = 0;
#pragma unroll
        for (int k = 0; k < 8; k++) c0 += hist[(b0 << 3) + k];
        if (bpt == 2) {
#pragma unroll
            for (int k = 0; k < 8; k++) c1 += hist[((b0 + 1) << 3) + k];
        }
        uint s = c0 + c1;
        uint sc = s;
#pragma unroll
        for (int o = 1; o < 64; o <<= 1) {
            uint t2 = __shfl_up(sc, o, 64);
            if ((tid & 63) >= o) sc += t2;
        }
        if ((tid & 63) == 63) wsum[tid >> 6] = sc;
        __syncthreads();
        uint base = 0;
        for (int w = 0; w < (tid >> 6); w++) base += wsum[w];
        uint c = base + sc - s;            // exclusive start of this thread's bins
        if (rank >= c && rank < c + c0) { bc[0] = (uint)b0; bc[1] = rank - c; }
        c += c0;
        if (bpt == 2 && rank >= c && rank < c + c1) { bc[0] = (uint)(b0 + 1); bc[1] = rank - c; }
        __syncthreads();
        pref |= bc[0] << sh;
        rank = bc[1];
        __syncthreads();   // all reads of hist/wsum/bc done before next level's zeroing
    }
    if (tid == 0) {
        uint key = pref;
        uint bits = (key & 0x80000000u) ? (key ^ 0x80000000u) : ~key;
        scal[0] = __float_as_uint(sigmoid_exact(__uint_as_float(bits)));
    }
}

// ---------------- K2: thresh+eff fused (sigmoid loop 4-way batched) -------------------
__global__ __launch_bounds__(256) void k_threff(const float* __restrict__ adj_param,
                                                const uint* __restrict__ scal,
                                                const float* __restrict__ gpW1,
                                                float* __restrict__ adj_out,
                                                ushort* __restrict__ effF) {
    __shared__ ushort adjS[16384] __attribute__((aligned(16)));  // A-frags: 64 j x 256 i
    __shared__ ushort Bf[16384] __attribute__((aligned(16)));    // 4 k-slabs x 4096 frags
    int d = blockIdx.x, jt = blockIdx.y, tid = threadIdx.x;
    float thr = __uint_as_float(scal[0]);

    {
        int jl = tid & 63;
        int jglob = jt * 64 + jl;
        int wrow = tid >> 6;          // 4 waves, 4 interleaved rows
#pragma unroll 1
        for (int i = 0; i < 16; i++) {
            float p[4];
#pragma unroll
            for (int u = 0; u < 4; u++)
                p[u] = adj_param[(size_t)((i * 4 + u) * 4 + wrow) * 256 + jglob];
#pragma unroll
            for (int u = 0; u < 4; u++) {
                int ir = (i * 4 + u) * 4 + wrow;    // 0..255
                float s = sigmoid_exact(p[u]);
                float v = (s > thr && ir != jglob) ? s : 0.0f;
                adjS[afrag_off(jl, ir)] = f2bf(v);
                if (d == 0) adj_out[(size_t)ir * 256 + jglob] = v;
            }
        }
    }
#pragma unroll
    for (int t = 0; t < 16; t++) {
        int idx = t * 256 + tid;
        int i = idx >> 4;
        int f4 = idx & 15;
        float4 v = *(const float4*)(gpW1 + ((size_t)i * 64 + d) * 64 + f4 * 4);
        int slab = i >> 6, il = i & 63, e0 = f4 * 4;
        Bf[slab * 4096 + wfrag_off(e0 + 0, il)] = f2bf(v.x);
        Bf[slab * 4096 + wfrag_off(e0 + 1, il)] = f2bf(v.y);
        Bf[slab * 4096 + wfrag_off(e0 + 2, il)] = f2bf(v.z);
        Bf[slab * 4096 + wfrag_off(e0 + 3, il)] = f2bf(v.w);
    }
    __syncthreads();
    int wid = tid >> 6, lane = tid & 63, quad = lane >> 4, l16 = lane & 15;
    f32x4 acc[4];
#pragma unroll
    for (int nt = 0; nt < 4; nt++) acc[nt] = (f32x4){0.f, 0.f, 0.f, 0.f};
#pragma unroll
    for (int ks8 = 0; ks8 < 8; ks8++) {
        short8 af = *(const short8*)&adjS[((((wid * 8 + ks8) * 4 + quad) * 16 + l16)) * 8];
        int slab = ks8 >> 1, ks = ks8 & 1;
#pragma unroll
        for (int nt = 0; nt < 4; nt++) {
            short8 bf = *(const short8*)&Bf[slab * 4096 + (((nt * 2 + ks) * 4 + quad) * 16 + l16) * 8];
            acc[nt] = __builtin_amdgcn_mfma_f32_16x16x32_bf16(af, bf, acc[nt], 0, 0, 0);
        }
    }
#pragma unroll
    for (int nt = 0; nt < 4; nt++) {
        int e = nt * 16 + l16;
#pragma unroll
        for (int r = 0; r < 4; r++) {
            int j = jt * 64 + wid * 16 + quad * 4 + r;
            float w = gpW1[((size_t)j * 64 + d) * 64 + e];
            float eff = 0.5f * (acc[nt][r] + w);
            effF[(size_t)j * 4096 + wfrag_off(e, d)] = f2bf(eff);
        }
    }
}

// ---------------- K3: fused MLP+gp (R5-verified best variant) -------------------------
// 8-node groups, 1024 blocks = 4/CU. Single-buffer LDS (33 KB) + reg-staged prefetch
// of next node's weights/x/biases.
__global__ __launch_bounds__(256, 4) void k_fused(const float* __restrict__ x,
                                                  const ushort* __restrict__ W1f,
                                                  const ushort* __restrict__ W2f,
                                                  const ushort* __restrict__ effF,
                                                  const float* __restrict__ b1,
                                                  const float* __restrict__ b2,
                                                  float* __restrict__ gparts) {
    __shared__ ushort Wf1[4096] __attribute__((aligned(16)));
    __shared__ ushort Wf2[4096] __attribute__((aligned(16)));
    __shared__ ushort Ef[4096] __attribute__((aligned(16)));
    __shared__ ushort St[4][16 * 72];    // per-wave staging (stride 72: 2-way-free banks)
    int tid = threadIdx.x;
    int g = blockIdx.x, bt = blockIdx.y;
    int wid = tid >> 6, lane = tid & 63, quad = lane >> 4, l16 = lane & 15;
    int rbase = bt * 64 + wid * 16;
    ushort* Sw = &St[wid][0];
    const float* xrow = x + (size_t)(rbase + l16) * ND_ + quad * 8;

    // ---- prologue: node 0 weights->regs->LDS, x->regs, biases->regs ----
    int n0 = g * 8;
    uint4 w1a = ((const uint4*)(W1f + (size_t)n0 * 4096))[tid];
    uint4 w1b = ((const uint4*)(W1f + (size_t)n0 * 4096))[256 + tid];
    uint4 w2a = ((const uint4*)(W2f + (size_t)n0 * 4096))[tid];
    uint4 w2b = ((const uint4*)(W2f + (size_t)n0 * 4096))[256 + tid];
    uint4 ea  = ((const uint4*)(effF + (size_t)n0 * 4096))[tid];
    uint4 eb  = ((const uint4*)(effF + (size_t)n0 * 4096))[256 + tid];
    float4 xr0, xr1, xr2, xr3;
    {
        const float* xp = xrow + (size_t)n0 * 64;
        xr0 = *(const float4*)(xp);
        xr1 = *(const float4*)(xp + 4);
        xr2 = *(const float4*)(xp + 32);
        xr3 = *(const float4*)(xp + 36);
    }
    float b1n[4], b2n[4];
#pragma unroll
    for (int nt = 0; nt < 4; nt++) {
        b1n[nt] = b1[n0 * 64 + nt * 16 + l16];
        b2n[nt] = b2[n0 * 64 + nt * 16 + l16];
    }
    ((uint4*)Wf1)[tid] = w1a;  ((uint4*)Wf1)[256 + tid] = w1b;
    ((uint4*)Wf2)[tid] = w2a;  ((uint4*)Wf2)[256 + tid] = w2b;
    ((uint4*)Ef)[tid]  = ea;   ((uint4*)Ef)[256 + tid]  = eb;

    f32x4 accg[4];
#pragma unroll
    for (int nt = 0; nt < 4; nt++) accg[nt] = (f32x4){0.f, 0.f, 0.f, 0.f};

    __syncthreads();   // node-0 weights visible

#pragma unroll 1
    for (int nl = 0; nl < 8; nl++) {
        // current node's x -> A-frags, biases -> locals (before regs are overwritten)
        short8 fa0, fa1;
        {
            short8 a;
            a[0] = (short)f2bf(xr0.x); a[1] = (short)f2bf(xr0.y);
            a[2] = (short)f2bf(xr0.z); a[3] = (short)f2bf(xr0.w);
            a[4] = (short)f2bf(xr1.x); a[5] = (short)f2bf(xr1.y);
            a[6] = (short)f2bf(xr1.z); a[7] = (short)f2bf(xr1.w);
            fa0 = a;
            short8 b;
            b[0] = (short)f2bf(xr2.x); b[1] = (short)f2bf(xr2.y);
            b[2] = (short)f2bf(xr2.z); b[3] = (short)f2bf(xr2.w);
            b[4] = (short)f2bf(xr3.x); b[5] = (short)f2bf(xr3.y);
            b[6] = (short)f2bf(xr3.z); b[7] = (short)f2bf(xr3.w);
            fa1 = b;
        }
        float bias1[4], bias2[4];
#pragma unroll
        for (int nt = 0; nt < 4; nt++) { bias1[nt] = b1n[nt]; bias2[nt] = b2n[nt]; }

        // prefetch node nl+1 into registers
        if (nl < 7) {
            int nn = g * 8 + nl + 1;
            w1a = ((const uint4*)(W1f + (size_t)nn * 4096))[tid];
            w1b = ((const uint4*)(W1f + (size_t)nn * 4096))[256 + tid];
            w2a = ((const uint4*)(W2f + (size_t)nn * 4096))[tid];
            w2b = ((const uint4*)(W2f + (size_t)nn * 4096))[256 + tid];
            ea  = ((const uint4*)(effF + (size_t)nn * 4096))[tid];
            eb  = ((const uint4*)(effF + (size_t)nn * 4096))[256 + tid];
            const float* xp = xrow + (size_t)nn * 64;
            xr0 = *(const float4*)(xp);
            xr1 = *(const float4*)(xp + 4);
            xr2 = *(const float4*)(xp + 32);
            xr3 = *(const float4*)(xp + 36);
#pragma unroll
            for (int nt = 0; nt < 4; nt++) {
                b1n[nt] = b1[nn * 64 + nt * 16 + l16];
                b2n[nt] = b2[nn * 64 + nt * 16 + l16];
            }
        }

        // layer 1
        f32x4 acc[4];
#pragma unroll
        for (int nt = 0; nt < 4; nt++) acc[nt] = (f32x4){0.f, 0.f, 0.f, 0.f};
#pragma unroll
        for (int nt = 0; nt < 4; nt++) {
            short8 bf = *(const short8*)&Wf1[(((nt * 2 + 0) * 4 + quad) * 16 + l16) * 8];
            acc[nt] = __builtin_amdgcn_mfma_f32_16x16x32_bf16(fa0, bf, acc[nt], 0, 0, 0);
        }
#pragma unroll
        for (int nt = 0; nt < 4; nt++) {
            short8 bf = *(const short8*)&Wf1[(((nt * 2 + 1) * 4 + quad) * 16 + l16) * 8];
            acc[nt] = __builtin_amdgcn_mfma_f32_16x16x32_bf16(fa1, bf, acc[nt], 0, 0, 0);
        }
#pragma unroll
        for (int nt = 0; nt < 4; nt++)
#pragma unroll
            for (int r = 0; r < 4; r++) {
                float h = fmaxf(acc[nt][r] + bias1[nt], 0.0f);
                Sw[(quad * 4 + r) * 72 + nt * 16 + l16] = f2bf(h);
            }
        // layer 2
        f32x4 acc2[4];
#pragma unroll
        for (int nt = 0; nt < 4; nt++) acc2[nt] = (f32x4){0.f, 0.f, 0.f, 0.f};
#pragma unroll
        for (int ks = 0; ks < 2; ks++) {
            short8 a2 = *(const short8*)&Sw[l16 * 72 + ks * 32 + quad * 8];
#pragma unroll
            for (int nt = 0; nt < 4; nt++) {
                short8 bf = *(const short8*)&Wf2[(((nt * 2 + ks) * 4 + quad) * 16 + l16) * 8];
                acc2[nt] = __builtin_amdgcn_mfma_f32_16x16x32_bf16(a2, bf, acc2[nt], 0, 0, 0);
            }
        }
#pragma unroll
        for (int nt = 0; nt < 4; nt++)
#pragma unroll
            for (int r = 0; r < 4; r++) {
                float v = acc2[nt][r] + bias2[nt];
                Sw[(quad * 4 + r) * 72 + nt * 16 + l16] = f2bf(v);
            }
        // gp projection
#pragma unroll
        for (int ks = 0; ks < 2; ks++) {
            short8 a3 = *(const short8*)&Sw[l16 * 72 + ks * 32 + quad * 8];
#pragma unroll
            for (int nt = 0; nt < 4; nt++) {
                short8 bf = *(const short8*)&Ef[(((nt * 2 + ks) * 4 + quad) * 16 + l16) * 8];
                accg[nt] = __builtin_amdgcn_mfma_f32_16x16x32_bf16(a3, bf, accg[nt], 0, 0, 0);
            }
        }

        if (nl < 7) {
            __syncthreads();   // WAR: all waves done reading this node's weights
            ((uint4*)Wf1)[tid] = w1a;  ((uint4*)Wf1)[256 + tid] = w1b;
            ((uint4*)Wf2)[tid] = w2a;  ((uint4*)Wf2)[256 + tid] = w2b;
            ((uint4*)Ef)[tid]  = ea;   ((uint4*)Ef)[256 + tid]  = eb;
            __syncthreads();   // RAW: next node's weights visible
        }
    }

    // write fp32 partials for this node-group
    float* gp = gparts + ((size_t)g * B_ + bt * 64) * 64;
#pragma unroll
    for (int nt = 0; nt < 4; nt++)
#pragma unroll
        for (int r = 0; r < 4; r++) {
            int b_loc = wid * 16 + quad * 4 + r;
            int e = nt * 16 + l16;
            gp[b_loc * 64 + e] = accg[nt][r];
        }
}

// ---------------- K4: reduce partials, bias+relu, gp2 (fp32); 4 rows/block ------------
__global__ __launch_bounds__(256) void k_gp2(const float* __restrict__ gparts,
                                             const float* __restrict__ gpb1,
                                             const float* __restrict__ gpW2,
                                             const float* __restrict__ gpb2,
                                             float* __restrict__ out) {
    __shared__ float gs[4][64];
    int b0 = blockIdx.x * 4, tid = threadIdx.x;
    int r = tid >> 6, e = tid & 63;
    float s = gpb1[e];
#pragma unroll
    for (int p = 0; p < NGROUPS; p++)
        s += gparts[((size_t)p * B_ + b0 + r) * 64 + e];
    gs[r][e] = fmaxf(s, 0.0f);
    __syncthreads();
    if (tid < 128) {
        int rr = tid >> 5, o = tid & 31;
        float a = gpb2[o];
#pragma unroll 8
        for (int k2 = 0; k2 < 64; k2++) a += gs[rr][k2] * gpW2[k2 * 32 + o];
        out[(size_t)(b0 + rr) * 32 + o] = a;
    }
}

extern "C" void kernel_launch(void* const* d_in, const int* in_sizes, int n_in,
                              void* d_out, int out_size, void* d_ws, size_t ws_size,
                              hipStream_t stream) {
    const float* x = (const float*)d_in[0];
    const float* adj_param = (const float*)d_in[1];
    const float* W1 = (const float*)d_in[2];
    const float* b1 = (const float*)d_in[3];
    const float* W2 = (const float*)d_in[4];
    const float* b2 = (const float*)d_in[5];
    const float* gpW1 = (const float*)d_in[6];
    const float* gpb1 = (const float*)d_in[7];
    const float* gpW2 = (const float*)d_in[8];
    const float* gpb2 = (const float*)d_in[9];

    float* out = (float*)d_out;                 // [2048*32]
    float* adj_out = (float*)d_out + NN_;       // [256*256]

    char* ws = (char*)d_ws;
    ushort* W1f = (ushort*)(ws + WS_W1T);
    ushort* W2f = (ushort*)(ws + WS_W2T);
    ushort* effF = (ushort*)(ws + WS_EFF);
    float* gparts = (float*)(ws + WS_GPARTS);
    uint* scal = (uint*)(ws + WS_SCAL);

    k_cvt_radix<<<129, 1024, 0, stream>>>(W1, W2, adj_param, W1f, W2f, scal);
    k_threff<<<dim3(64, 4), 256, 0, stream>>>(adj_param, scal, gpW1, adj_out, effF);
    k_fused<<<dim3(NGROUPS, 32), 256, 0, stream>>>(x, W1f, W2f, effF, b1, b2, gparts);
    k_gp2<<<512, 256, 0, stream>>>(gparts, gpb1, gpW2, gpb2, out);
}

// Round 9
// 269.676 us; speedup vs baseline: 1.2520x; 1.0140x over previous
//
#include <hip/hip_runtime.h>
#include <math.h>

typedef unsigned int uint;
typedef unsigned short ushort;
typedef short short8 __attribute__((ext_vector_type(8)));
typedef float f32x4 __attribute__((ext_vector_type(4)));

#define B_ 2048
#define N_ 256
#define D_ 64
#define ND_ 16384
#define NN_ 65536
#define KIDX_ 52428u
#define NGROUPS 32   // split-K over node groups (8 nodes each) for the fused gp partials

// ---------------- ws layout (bytes) ----------------
#define WS_W1T    ((size_t)0)                    // packed W1 B-frags bf16 : 2 MiB
#define WS_W2T    ((size_t)2*1024*1024)          // packed W2 B-frags bf16 : 2 MiB
#define WS_EFF    ((size_t)4*1024*1024)          // gpW1eff B-frags bf16 [256 nodes][4096] : 2 MiB
#define WS_GPARTS ((size_t)8*1024*1024)          // f32 [32][2048][64] : 16 MiB
#define WS_SCAL   ((size_t)24*1024*1024)         // threshold scalar

__device__ __forceinline__ ushort f2bf(float f) {
    uint u = __float_as_uint(f);
    u += 0x7fffu + ((u >> 16) & 1u);
    return (ushort)(u >> 16);
}
__device__ __forceinline__ float bf2f(ushort u) { return __uint_as_float(((uint)u) << 16); }

// exact float sigmoid via correctly-rounded double exp (matches numpy; verified)
__device__ __forceinline__ float sigmoid_exact(float a) {
    float t = (float)exp(-(double)a);
    return 1.0f / (1.0f + t);
}

// float bits -> ascending-order uint key (same transform as prior verified rounds)
__device__ __forceinline__ uint f2key(uint bits) {
    return bits ^ ((bits & 0x80000000u) ? 0xFFFFFFFFu : 0x80000000u);
}

// B-fragment offset for 16x16x32 bf16: element (e=outcol, k) of a 64x64 W-slice.
__device__ __forceinline__ int wfrag_off(int e, int k) {
    return ((((e >> 4) * 2 + (k >> 5)) * 4 + ((k >> 3) & 3)) * 16 + (e & 15)) * 8 + (k & 7);
}

// A-fragment offset (local j in [0,64), i in [0,256))
__device__ __forceinline__ int afrag_off(int jl, int i) {
    return (((((jl >> 4) * 8 + (i >> 5)) * 4 + ((i >> 3) & 3)) * 16) + (jl & 15)) * 8 + (i & 7);
}

// ---------------- K1: radix select (block 0: 3-level MSD histogram) +
// weight convert (blocks 1..128, four 256-thread quarters per block) ------------------
__global__ __launch_bounds__(1024) void k_cvt_radix(const float* __restrict__ W1,
                                                    const float* __restrict__ W2,
                                                    const float* __restrict__ adj_param,
                                                    ushort* __restrict__ W1f,
                                                    ushort* __restrict__ W2f,
                                                    uint* __restrict__ scal) {
    __shared__ uint SH[16402] __attribute__((aligned(16)));   // 64 KB hist + scan scratch
    int bid = blockIdx.x, tid = threadIdx.x;

    if (bid != 0) {
        // ---- convert: quarter q handles matrix m ----
        int q = tid >> 8, t = tid & 255;
        int m = (bid - 1) * 4 + q;
        ushort* P = (ushort*)SH + q * 4096;
        const float* src = (m < 256) ? W1 + (size_t)m * 4096 : W2 + (size_t)(m - 256) * 4096;
#pragma unroll
        for (int i = 0; i < 16; i++) {
            int idx = i * 256 + t;
            int k = idx >> 6, e = idx & 63;   // src is [k][e]
            P[wfrag_off(e, k)] = f2bf(src[idx]);
        }
        __syncthreads();
        ushort* dst = (m < 256) ? W1f + (size_t)m * 4096 : W2f + (size_t)(m - 256) * 4096;
#pragma unroll
        for (int i = 0; i < 2; i++)
            ((uint4*)dst)[i * 256 + t] = ((const uint4*)P)[i * 256 + t];
        return;
    }

    // ---- radix block: 3-level MSD histogram select (11+11+10 bits), no spills ----
    uint* hist = SH;                  // up to [2048][8] uint = 64 KB
    uint* wsum = SH + 16384;          // 16 wave totals
    uint* bc   = SH + 16400;          // bc[0]=chosen bin, bc[1]=residual rank
    const uint4* pv = (const uint4*)adj_param;
    uint rank = KIDX_;
    uint pref = 0u;
#pragma unroll 1
    for (int lvl = 0; lvl < 3; lvl++) {
        int nb  = (lvl == 2) ? 1024 : 2048;
        int sh  = (lvl == 0) ? 21 : (lvl == 1) ? 10 : 0;
        uint pm = (lvl == 0) ? 0u : (lvl == 1) ? 0xFFE00000u : 0xFFFFFC00u;
        for (int i = tid; i < nb * 8; i += 1024) hist[i] = 0u;
        __syncthreads();
        int sub = tid & 7;
#pragma unroll 1
        for (int i = 0; i < 16; i++) {
            uint4 v = pv[i * 1024 + tid];
#define H_(B) { uint k_ = f2key(B); if (((k_ ^ pref) & pm) == 0u) \
                atomicAdd(&hist[(((k_ >> sh) & (uint)(nb - 1)) << 3) + sub], 1u); }
            H_(v.x) H_(v.y) H_(v.z) H_(v.w)
#undef H_
        }
        __syncthreads();
        int bpt = nb >> 10;                // bins per thread: 2 (lvl 0/1) or 1 (lvl 2)
        int b0 = tid * bpt;
        uint c0 = 0, c1 = 0;
#pragma unroll
        for (int k = 0; k < 8; k++) c0 += hist[(b0 << 3) + k];
        if (bpt == 2) {
#pragma unroll
            for (int k = 0; k < 8; k++) c1 += hist[((b0 + 1) << 3) + k];
        }
        uint s = c0 + c1;
        uint sc = s;
#pragma unroll
        for (int o = 1; o < 64; o <<= 1) {
            uint t2 = __shfl_up(sc, o, 64);
            if ((tid & 63) >= o) sc += t2;
        }
        if ((tid & 63) == 63) wsum[tid >> 6] = sc;
        __syncthreads();
        uint base = 0;
        for (int w = 0; w < (tid >> 6); w++) base += wsum[w];
        uint c = base + sc - s;            // exclusive start of this thread's bins
        if (rank >= c && rank < c + c0) { bc[0] = (uint)b0; bc[1] = rank - c; }
        c += c0;
        if (bpt == 2 && rank >= c && rank < c + c1) { bc[0] = (uint)(b0 + 1); bc[1] = rank - c; }
        __syncthreads();
        pref |= bc[0] << sh;
        rank = bc[1];
        __syncthreads();   // all reads of hist/wsum/bc done before next level's zeroing
    }
    if (tid == 0) {
        uint key = pref;
        uint bits = (key & 0x80000000u) ? (key ^ 0x80000000u) : ~key;
        scal[0] = __float_as_uint(sigmoid_exact(__uint_as_float(bits)));
    }
}

// ---------------- K2: thresh+eff fused (sigmoid loop 4-way batched) -------------------
__global__ __launch_bounds__(256) void k_threff(const float* __restrict__ adj_param,
                                                const uint* __restrict__ scal,
                                                const float* __restrict__ gpW1,
                                                float* __restrict__ adj_out,
                                                ushort* __restrict__ effF) {
    __shared__ ushort adjS[16384] __attribute__((aligned(16)));  // A-frags: 64 j x 256 i
    __shared__ ushort Bf[16384] __attribute__((aligned(16)));    // 4 k-slabs x 4096 frags
    int d = blockIdx.x, jt = blockIdx.y, tid = threadIdx.x;
    float thr = __uint_as_float(scal[0]);

    {
        int jl = tid & 63;
        int jglob = jt * 64 + jl;
        int wrow = tid >> 6;          // 4 waves, 4 interleaved rows
#pragma unroll 1
        for (int i = 0; i < 16; i++) {
            float p[4];
#pragma unroll
            for (int u = 0; u < 4; u++)
                p[u] = adj_param[(size_t)((i * 4 + u) * 4 + wrow) * 256 + jglob];
#pragma unroll
            for (int u = 0; u < 4; u++) {
                int ir = (i * 4 + u) * 4 + wrow;    // 0..255
                float s = sigmoid_exact(p[u]);
                float v = (s > thr && ir != jglob) ? s : 0.0f;
                adjS[afrag_off(jl, ir)] = f2bf(v);
                if (d == 0) adj_out[(size_t)ir * 256 + jglob] = v;
            }
        }
    }
#pragma unroll
    for (int t = 0; t < 16; t++) {
        int idx = t * 256 + tid;
        int i = idx >> 4;
        int f4 = idx & 15;
        float4 v = *(const float4*)(gpW1 + ((size_t)i * 64 + d) * 64 + f4 * 4);
        int slab = i >> 6, il = i & 63, e0 = f4 * 4;
        Bf[slab * 4096 + wfrag_off(e0 + 0, il)] = f2bf(v.x);
        Bf[slab * 4096 + wfrag_off(e0 + 1, il)] = f2bf(v.y);
        Bf[slab * 4096 + wfrag_off(e0 + 2, il)] = f2bf(v.z);
        Bf[slab * 4096 + wfrag_off(e0 + 3, il)] = f2bf(v.w);
    }
    __syncthreads();
    int wid = tid >> 6, lane = tid & 63, quad = lane >> 4, l16 = lane & 15;
    f32x4 acc[4];
#pragma unroll
    for (int nt = 0; nt < 4; nt++) acc[nt] = (f32x4){0.f, 0.f, 0.f, 0.f};
#pragma unroll
    for (int ks8 = 0; ks8 < 8; ks8++) {
        short8 af = *(const short8*)&adjS[((((wid * 8 + ks8) * 4 + quad) * 16 + l16)) * 8];
        int slab = ks8 >> 1, ks = ks8 & 1;
#pragma unroll
        for (int nt = 0; nt < 4; nt++) {
            short8 bf = *(const short8*)&Bf[slab * 4096 + (((nt * 2 + ks) * 4 + quad) * 16 + l16) * 8];
            acc[nt] = __builtin_amdgcn_mfma_f32_16x16x32_bf16(af, bf, acc[nt], 0, 0, 0);
        }
    }
#pragma unroll
    for (int nt = 0; nt < 4; nt++) {
        int e = nt * 16 + l16;
#pragma unroll
        for (int r = 0; r < 4; r++) {
            int j = jt * 64 + wid * 16 + quad * 4 + r;
            float w = gpW1[((size_t)j * 64 + d) * 64 + e];
            float eff = 0.5f * (acc[nt][r] + w);
            effF[(size_t)j * 4096 + wfrag_off(e, d)] = f2bf(eff);
        }
    }
}

// ---------------- K3: fused MLP+gp, v6: 512-thread blocks, 128 rows/block -------------
// Halves per-node overhead per unit work: each weight staging serves 8 waves (128 rows);
// per-thread staging = 3 uint4 loads + 3 ds_writes (512 threads cover 24 KB exactly);
// total barrier events halve. Biases staged to LDS once. Grid 32x16 = 512 blocks = 2/CU
// of 8 waves (16 waves/CU).
__global__ __launch_bounds__(512, 4) void k_fused(const float* __restrict__ x,
                                                  const ushort* __restrict__ W1f,
                                                  const ushort* __restrict__ W2f,
                                                  const ushort* __restrict__ effF,
                                                  const float* __restrict__ b1,
                                                  const float* __restrict__ b2,
                                                  float* __restrict__ gparts) {
    __shared__ ushort Wf1[4096] __attribute__((aligned(16)));
    __shared__ ushort Wf2[4096] __attribute__((aligned(16)));
    __shared__ ushort Ef[4096] __attribute__((aligned(16)));
    __shared__ ushort St[8][16 * 72];    // per-wave staging (stride 72: 2-way-free banks)
    __shared__ float Bs[2][8][64];       // biases for the 8 nodes of the group
    int tid = threadIdx.x;
    int g = blockIdx.x, bt = blockIdx.y;
    int wid = tid >> 6, lane = tid & 63, quad = lane >> 4, l16 = lane & 15;
    int rbase = bt * 128 + wid * 16;
    ushort* Sw = &St[wid][0];
    const float* xrow = x + (size_t)(rbase + l16) * ND_ + quad * 8;

    // stage biases once (coalesced): 2 x 512 floats, one per thread
    ((float*)Bs[0])[tid] = b1[(size_t)g * 512 + tid];
    ((float*)Bs[1])[tid] = b2[(size_t)g * 512 + tid];

    // ---- prologue: node 0 weights->regs->LDS (1 uint4 per array per thread), x->regs
    int n0 = g * 8;
    uint4 w1a = ((const uint4*)(W1f + (size_t)n0 * 4096))[tid];
    uint4 w2a = ((const uint4*)(W2f + (size_t)n0 * 4096))[tid];
    uint4 ea  = ((const uint4*)(effF + (size_t)n0 * 4096))[tid];
    float4 xr0, xr1, xr2, xr3;
    {
        const float* xp = xrow + (size_t)n0 * 64;
        xr0 = *(const float4*)(xp);
        xr1 = *(const float4*)(xp + 4);
        xr2 = *(const float4*)(xp + 32);
        xr3 = *(const float4*)(xp + 36);
    }
    ((uint4*)Wf1)[tid] = w1a;
    ((uint4*)Wf2)[tid] = w2a;
    ((uint4*)Ef)[tid]  = ea;

    f32x4 accg[4];
#pragma unroll
    for (int nt = 0; nt < 4; nt++) accg[nt] = (f32x4){0.f, 0.f, 0.f, 0.f};

    __syncthreads();   // node-0 weights + Bs visible

#pragma unroll 1
    for (int nl = 0; nl < 8; nl++) {
        // current node's x -> A-frags (before xr regs are overwritten)
        short8 fa0, fa1;
        {
            short8 a;
            a[0] = (short)f2bf(xr0.x); a[1] = (short)f2bf(xr0.y);
            a[2] = (short)f2bf(xr0.z); a[3] = (short)f2bf(xr0.w);
            a[4] = (short)f2bf(xr1.x); a[5] = (short)f2bf(xr1.y);
            a[6] = (short)f2bf(xr1.z); a[7] = (short)f2bf(xr1.w);
            fa0 = a;
            short8 b;
            b[0] = (short)f2bf(xr2.x); b[1] = (short)f2bf(xr2.y);
            b[2] = (short)f2bf(xr2.z); b[3] = (short)f2bf(xr2.w);
            b[4] = (short)f2bf(xr3.x); b[5] = (short)f2bf(xr3.y);
            b[6] = (short)f2bf(xr3.z); b[7] = (short)f2bf(xr3.w);
            fa1 = b;
        }

        // prefetch node nl+1 into registers (3 weight uint4 + 4 x float4)
        if (nl < 7) {
            int nn = g * 8 + nl + 1;
            w1a = ((const uint4*)(W1f + (size_t)nn * 4096))[tid];
            w2a = ((const uint4*)(W2f + (size_t)nn * 4096))[tid];
            ea  = ((const uint4*)(effF + (size_t)nn * 4096))[tid];
            const float* xp = xrow + (size_t)nn * 64;
            xr0 = *(const float4*)(xp);
            xr1 = *(const float4*)(xp + 4);
            xr2 = *(const float4*)(xp + 32);
            xr3 = *(const float4*)(xp + 36);
        }

        float bias1[4], bias2[4];
#pragma unroll
        for (int nt = 0; nt < 4; nt++) {
            bias1[nt] = Bs[0][nl][nt * 16 + l16];
            bias2[nt] = Bs[1][nl][nt * 16 + l16];
        }

        // layer 1
        f32x4 acc[4];
#pragma unroll
        for (int nt = 0; nt < 4; nt++) acc[nt] = (f32x4){0.f, 0.f, 0.f, 0.f};
#pragma unroll
        for (int nt = 0; nt < 4; nt++) {
            short8 bf = *(const short8*)&Wf1[(((nt * 2 + 0) * 4 + quad) * 16 + l16) * 8];
            acc[nt] = __builtin_amdgcn_mfma_f32_16x16x32_bf16(fa0, bf, acc[nt], 0, 0, 0);
        }
#pragma unroll
        for (int nt = 0; nt < 4; nt++) {
            short8 bf = *(const short8*)&Wf1[(((nt * 2 + 1) * 4 + quad) * 16 + l16) * 8];
            acc[nt] = __builtin_amdgcn_mfma_f32_16x16x32_bf16(fa1, bf, acc[nt], 0, 0, 0);
        }
#pragma unroll
        for (int nt = 0; nt < 4; nt++)
#pragma unroll
            for (int r = 0; r < 4; r++) {
                float h = fmaxf(acc[nt][r] + bias1[nt], 0.0f);
                Sw[(quad * 4 + r) * 72 + nt * 16 + l16] = f2bf(h);
            }
        // layer 2
        f32x4 acc2[4];
#pragma unroll
        for (int nt = 0; nt < 4; nt++) acc2[nt] = (f32x4){0.f, 0.f, 0.f, 0.f};
#pragma unroll
        for (int ks = 0; ks < 2; ks++) {
            short8 a2 = *(const short8*)&Sw[l16 * 72 + ks * 32 + quad * 8];
#pragma unroll
            for (int nt = 0; nt < 4; nt++) {
                short8 bf = *(const short8*)&Wf2[(((nt * 2 + ks) * 4 + quad) * 16 + l16) * 8];
                acc2[nt] = __builtin_amdgcn_mfma_f32_16x16x32_bf16(a2, bf, acc2[nt], 0, 0, 0);
            }
        }
#pragma unroll
        for (int nt = 0; nt < 4; nt++)
#pragma unroll
            for (int r = 0; r < 4; r++) {
                float v = acc2[nt][r] + bias2[nt];
                Sw[(quad * 4 + r) * 72 + nt * 16 + l16] = f2bf(v);
            }
        // gp projection
#pragma unroll
        for (int ks = 0; ks < 2; ks++) {
            short8 a3 = *(const short8*)&Sw[l16 * 72 + ks * 32 + quad * 8];
#pragma unroll
            for (int nt = 0; nt < 4; nt++) {
                short8 bf = *(const short8*)&Ef[(((nt * 2 + ks) * 4 + quad) * 16 + l16) * 8];
                accg[nt] = __builtin_amdgcn_mfma_f32_16x16x32_bf16(a3, bf, accg[nt], 0, 0, 0);
            }
        }

        if (nl < 7) {
            __syncthreads();   // WAR: all waves done reading this node's weights
            ((uint4*)Wf1)[tid] = w1a;
            ((uint4*)Wf2)[tid] = w2a;
            ((uint4*)Ef)[tid]  = ea;
            __syncthreads();   // RAW: next node's weights visible
        }
    }

    // write fp32 partials for this node-group (128 rows)
    float* gp = gparts + ((size_t)g * B_ + bt * 128) * 64;
#pragma unroll
    for (int nt = 0; nt < 4; nt++)
#pragma unroll
        for (int r = 0; r < 4; r++) {
            int b_loc = wid * 16 + quad * 4 + r;
            int e = nt * 16 + l16;
            gp[b_loc * 64 + e] = accg[nt][r];
        }
}

// ---------------- K4: reduce partials, bias+relu, gp2 (fp32); 4 rows/block ------------
__global__ __launch_bounds__(256) void k_gp2(const float* __restrict__ gparts,
                                             const float* __restrict__ gpb1,
                                             const float* __restrict__ gpW2,
                                             const float* __restrict__ gpb2,
                                             float* __restrict__ out) {
    __shared__ float gs[4][64];
    int b0 = blockIdx.x * 4, tid = threadIdx.x;
    int r = tid >> 6, e = tid & 63;
    float s = gpb1[e];
#pragma unroll
    for (int p = 0; p < NGROUPS; p++)
        s += gparts[((size_t)p * B_ + b0 + r) * 64 + e];
    gs[r][e] = fmaxf(s, 0.0f);
    __syncthreads();
    if (tid < 128) {
        int rr = tid >> 5, o = tid & 31;
        float a = gpb2[o];
#pragma unroll 8
        for (int k2 = 0; k2 < 64; k2++) a += gs[rr][k2] * gpW2[k2 * 32 + o];
        out[(size_t)(b0 + rr) * 32 + o] = a;
    }
}

extern "C" void kernel_launch(void* const* d_in, const int* in_sizes, int n_in,
                              void* d_out, int out_size, void* d_ws, size_t ws_size,
                              hipStream_t stream) {
    const float* x = (const float*)d_in[0];
    const float* adj_param = (const float*)d_in[1];
    const float* W1 = (const float*)d_in[2];
    const float* b1 = (const float*)d_in[3];
    const float* W2 = (const float*)d_in[4];
    const float* b2 = (const float*)d_in[5];
    const float* gpW1 = (const float*)d_in[6];
    const float* gpb1 = (const float*)d_in[7];
    const float* gpW2 = (const float*)d_in[8];
    const float* gpb2 = (const float*)d_in[9];

    float* out = (float*)d_out;                 // [2048*32]
    float* adj_out = (float*)d_out + NN_;       // [256*256]

    char* ws = (char*)d_ws;
    ushort* W1f = (ushort*)(ws + WS_W1T);
    ushort* W2f = (ushort*)(ws + WS_W2T);
    ushort* effF = (ushort*)(ws + WS_EFF);
    float* gparts = (float*)(ws + WS_GPARTS);
    uint* scal = (uint*)(ws + WS_SCAL);

    k_cvt_radix<<<129, 1024, 0, stream>>>(W1, W2, adj_param, W1f, W2f, scal);
    k_threff<<<dim3(64, 4), 256, 0, stream>>>(adj_param, scal, gpW1, adj_out, effF);
    k_fused<<<dim3(NGROUPS, 16), 512, 0, stream>>>(x, W1f, W2f, effF, b1, b2, gparts);
    k_gp2<<<512, 256, 0, stream>>>(gparts, gpb1, gpW2, gpb2, out);
}